// Round 11
// baseline (80.936 us; speedup 1.0000x reference)
//
#include <hip/hip_runtime.h>
#include <cmath>

// Problem constants (fixed by the reference's init kwargs):
//   POS_FREQS=31, W_MIN=0.1, W_MAX=1.0, PATCH=16 -> grid H=64 (row 63 padded), W=32
//   batch_triangles: [64,128,3,2] f32, lengths: [64] i32
//   outputs: mag [64,1,64,32] f32 then phase [64,1,64,32] f32, concatenated flat.
#define BB     64
#define MAXN   128
#define HH     64
#define WW     32
#define NFREQ  (HH*WW)      // 2048
#define BLK    256
#define NWAVE  4            // waves per block; each wave = 64 points' lanes
#define PGRPS  (NFREQ/64)   // 32 point-groups of 64 points per batch elem

// pos_w[k] = float32(0.1 * (10^(1/30))^k), k=0..30 — computed at "compile
// time" from the init kwargs (decimals carry ~1e-10 relative accuracy, far
// inside f32 half-ulp, so these round to the same bits numpy produces).
// Replaces the per-block double-precision pow() prologue (~2K cycles of
// software f64 per block while 3 waves waited at the barrier).
__device__ __constant__ float c_posw[31] = {
    0.10000000000f, 0.10797751623f, 0.11659144012f, 0.12589254118f,
    0.13593563909f, 0.14677992676f, 0.15848931925f, 0.17113283042f,
    0.18478497970f, 0.19952623150f, 0.21544346900f, 0.23263050672f,
    0.25118864315f, 0.27122725793f, 0.29286445646f, 0.31622776602f,
    0.34145488738f, 0.36869450645f, 0.39810717055f, 0.42986623483f,
    0.46415888336f, 0.50118723363f, 0.54116952655f, 0.58434141336f,
    0.63095734448f, 0.68129206906f, 0.73564225446f, 0.79432823472f,
    0.85769589859f, 0.92611872813f, 1.00000000000f
};

// sin(2*pi*x), cos(2*pi*x) via hardware v_sin_f32/v_cos_f32 (input in
// REVOLUTIONS, reduced to [0,1) with v_fract_f32 first).
__device__ __forceinline__ void sincos_2pi(float x, float* s, float* c) {
    float r = __builtin_amdgcn_fractf(x);
    *s = __builtin_amdgcn_sinf(r);
    *c = __builtin_amdgcn_cosf(r);
}

// Fully BRANCHLESS (point, triangle) evaluation — IDENTICAL text to the
// round-5/8/9 passing kernels (absmax 0.015625). Do not perturb.
// Rotated frame: E_x = exp(-2*pi*i*t_x), t_q = U*xq+V*yq, t_r = t_q+U_,
// t_s = t_r+V_.  All four reference cases share:
//   re =  A*c_s + B*c_r + C*c_q + D*s_r + E*s_q
//   im = -A*s_s - B*s_r - C*s_q + D*c_r + E*c_q
// with k = sgn*area/(4pi^2*den):
//   normal: A=-U_, B=S,  C=-V_, D=0,     E=0;     den=U_*V_*S, sgn=+2
//   diag  : A=0,   B=1,  C=-1,  D=0,     E=2piU_; den=U_^2,    sgn=-2
//   u_mask: A=1,   B=0,  C=-1,  D=0,     E=2piV_; den=V_^2,    sgn=-2
//   v_mask: A=0,   B=1,  C=-1,  D=2piU_, E=0;     den=U_^2,    sgn=+2
//   zero  : k=0, add area directly.
__device__ __forceinline__ void eval_tri(
    float U, float V, float4 A4, float4 B4, float& accR, float& accI,
    float TWOPI, float FOUR_PI2)
{
    const float xq = A4.x,  yq = A4.y,  e1x = A4.z, e1y = A4.w;
    const float e2x = B4.x, e2y = B4.y, area = B4.z;

    // Mask-determining quantities: plain mul/mul/add (no FMA contraction)
    // to reproduce the reference's exact-zero pattern.
    const float U_ = __fadd_rn(__fmul_rn(U, e1x), __fmul_rn(V, e1y));
    const float V_ = __fadd_rn(__fmul_rn(U, e2x), __fmul_rn(V, e2y));
    const float S  = __fadd_rn(U_, V_);

    const bool uz   = (U_ == 0.0f);
    const bool vz   = (V_ == 0.0f);
    const bool sz   = (S  == 0.0f);
    const bool zero = uz && vz;
    const bool diag = sz && !zero;      // uz -> (sz<->vz), so cases exclusive
    const bool u_m  = uz && !zero;
    const bool v_m  = vz && !zero;
    const bool nrm  = !(uz || vz || sz);

    // Exponential args (not mask-relevant; FMA fine). t_r/t_s exact when
    // U_/V_ are exactly 0 (adding exact zero), which the special cases need.
    const float t_q = U * xq + V * yq;
    const float t_r = t_q + U_;
    const float t_s = t_r + V_;

    float s_q, c_q, s_r, c_r, s_s, c_s;
    sincos_2pi(t_q, &s_q, &c_q);
    sincos_2pi(t_r, &s_r, &c_r);
    sincos_2pi(t_s, &s_s, &c_s);

    const float twU = TWOPI * U_;
    const float twV = TWOPI * V_;

    const float Ac = nrm ? -U_ : (u_m ? 1.0f : 0.0f);
    const float Bc = nrm ?  S  : ((diag || v_m) ? 1.0f : 0.0f);
    const float Cc = nrm ? -V_ : -1.0f;
    const float Dc = v_m  ? twU : 0.0f;
    const float Ec = diag ? twU : (u_m ? twV : 0.0f);

    const float d1  = u_m ? V_ : U_;
    const float den = nrm ? (U_ * V_) * S : d1 * d1;
    const float p1  = __builtin_amdgcn_rcpf(FOUR_PI2 * den);
    const float sgn = (diag || u_m) ? -2.0f : 2.0f;
    const float k   = zero ? 0.0f : sgn * area * p1;   // cndmask kills inf path

    const float re =  Ac * c_s + Bc * c_r + Cc * c_q + Dc * s_r + Ec * s_q;
    const float im = -(Ac * s_s + Bc * s_r + Cc * s_q) + Dc * c_r + Ec * c_q;

    accR = fmaf(k, re, accR) + (zero ? area : 0.0f);
    accI = fmaf(k, im, accI);
}

// ONE fused kernel (R9 structure): 4 waves share 64 points, split triangles
// stride-4 with wave-uniform scalar loads; LDS 4->1 reduction; direct output.
// R10 deltas: constant posw table (no f64, no prologue barrier) + explicit
// software pipeline on the triangle scalar loads.
__global__ __launch_bounds__(BLK) void poly_cft_fused(
    const float* __restrict__ tris,    // [64,128,3,2]
    const int*   __restrict__ lengths, // [64]
    float*       __restrict__ out)     // [2*64*2048]
{
    __shared__ float2 s_red[NWAVE][64];   // 2 KB

    const int pg   = blockIdx.x;           // 0..31 point group
    const int b    = blockIdx.y;           // 0..63 batch elem
    const int lane = threadIdx.x & 63;
    const int wv   = threadIdx.x >> 6;     // 0..3 wave id
    const int p    = (pg << 6) | lane;     // 0..2047 freq point
    const int h    = p >> 5;
    const int w    = p & 31;

    // U = Wx[h], V = Wy[w] straight from the constant table.
    float U;
    if (h < 31)       U = -c_posw[30 - h];
    else if (h == 31) U = 0.0f;
    else if (h < 63)  U = c_posw[h - 32];
    else              U = 0.0f;   // padded row (masked before output)
    const float V = (w == 0) ? 0.0f : c_posw[w - 1];

    // float32 constants exactly as the reference builds them:
    const float PI_F     = 3.14159274101257324f;   // np.float32(np.pi)
    const float TWOPI    = 6.28318548202514648f;   // 2*pi_f
    const float FOUR_PI2 = (4.0f * PI_F) * PI_F;   // np.float32(4)*pi*pi

    const int N = lengths[b];
    const float* __restrict__ tb = tris + (size_t)b * MAXN * 6;

    float accR = 0.0f, accI = 0.0f;

    // Wave wv handles triangles n = wv, wv+4, ... (wave-uniform index ->
    // scalar s_load path). Software pipeline: prefetch triangle n+4 while
    // evaluating n so the scalar-load latency hides behind the VALU work.
    int n = wv;
    float xq = 0.0f, yq = 0.0f, xr = 0.0f, yr = 0.0f, xs = 0.0f, ys = 0.0f;
    if (n < N) {
        const int nn = __builtin_amdgcn_readfirstlane(n);
        const float* t = tb + nn * 6;
        xq = t[0]; yq = t[1]; xr = t[2]; yr = t[3]; xs = t[4]; ys = t[5];
    }
    while (n < N) {
        const int n2 = n + NWAVE;
        float x2q = 0.0f, y2q = 0.0f, x2r = 0.0f, y2r = 0.0f, x2s = 0.0f, y2s = 0.0f;
        if (n2 < N) {
            const int nn2 = __builtin_amdgcn_readfirstlane(n2);
            const float* t2 = tb + nn2 * 6;
            x2q = t2[0]; y2q = t2[1]; x2r = t2[2]; y2r = t2[3]; x2s = t2[4]; y2s = t2[5];
        }

        const float det  = xq * (yr - ys) + xr * (ys - yq) + xs * (yq - yr);
        const float area = fabsf(0.5f * det);
        const float4 A4 = make_float4(xq, yq, xr - xq, yr - yq);
        const float4 B4 = make_float4(xs - xr, ys - yr, area, 0.0f);
        eval_tri(U, V, A4, B4, accR, accI, TWOPI, FOUR_PI2);

        n = n2;
        xq = x2q; yq = y2q; xr = x2r; yr = y2r; xs = x2s; ys = y2s;
    }

    s_red[wv][lane] = make_float2(accR, accI);
    __syncthreads();

    if (wv == 0) {
        float R = 0.0f, I = 0.0f;
#pragma unroll
        for (int k = 0; k < NWAVE; ++k) {
            const float2 v = s_red[k][lane];
            R += v.x;
            I += v.y;
        }
        // numpy's masked segment-sum adds exact +0.0 for invalid slots,
        // flipping -0.0 -> +0.0; reproduce (affects only zero signs).
        R += 0.0f;
        I += 0.0f;

        if (h == 63) { R = 0.0f; I = 0.0f; }   // pad row

        const float m2 = __fadd_rn(__fmul_rn(R, R), __fmul_rn(I, I));
        float mag, ph;
        if (m2 == 0.0f) {
            mag = 0.0f;
            ph  = atan2f(I, 1.0f);   // angle(0) = 0 semantics
        } else {
            mag = log1pf(sqrtf(m2));
            ph  = atan2f(I, R);
        }

        const int o = b * NFREQ + p;
        out[o]              = mag;   // mag block [64,1,64,32]
        out[BB * NFREQ + o] = ph;    // phase block follows
    }
}

extern "C" void kernel_launch(void* const* d_in, const int* in_sizes, int n_in,
                              void* d_out, int out_size, void* d_ws, size_t ws_size,
                              hipStream_t stream) {
    const float* tris    = (const float*)d_in[0]; // [64,128,3,2] f32
    const int*   lengths = (const int*)d_in[1];   // [64] i32
    float*       out     = (float*)d_out;         // [2*64*2048] f32

    poly_cft_fused<<<dim3(PGRPS, BB), dim3(BLK), 0, stream>>>(tris, lengths, out);
}

// Round 12
// 75.600 us; speedup vs baseline: 1.0706x; 1.0706x over previous
//
#include <hip/hip_runtime.h>
#include <cmath>

// Problem constants (fixed by the reference's init kwargs):
//   POS_FREQS=31, W_MIN=0.1, W_MAX=1.0, PATCH=16 -> grid H=64 (row 63 padded), W=32
//   batch_triangles: [64,128,3,2] f32, lengths: [64] i32
//   outputs: mag [64,1,64,32] f32 then phase [64,1,64,32] f32, concatenated flat.
#define BB     64
#define MAXN   128
#define HH     64
#define WW     32
#define NFREQ  (HH*WW)      // 2048
#define BLK    256
#define NWAVE  4            // waves per block; each wave covers 64 points
#define PGRPS  (NFREQ/64)   // 32 point-groups of 64 points per batch elem

// pos_w[k] = float32(0.1 * (10^(1/30))^k) — bit-exactness validated in R10
// (absmax unchanged vs the in-kernel f64 pow construction).
__device__ __constant__ float c_posw[31] = {
    0.10000000000f, 0.10797751623f, 0.11659144012f, 0.12589254118f,
    0.13593563909f, 0.14677992676f, 0.15848931925f, 0.17113283042f,
    0.18478497970f, 0.19952623150f, 0.21544346900f, 0.23263050672f,
    0.25118864315f, 0.27122725793f, 0.29286445646f, 0.31622776602f,
    0.34145488738f, 0.36869450645f, 0.39810717055f, 0.42986623483f,
    0.46415888336f, 0.50118723363f, 0.54116952655f, 0.58434141336f,
    0.63095734448f, 0.68129206906f, 0.73564225446f, 0.79432823472f,
    0.85769589859f, 0.92611872813f, 1.00000000000f
};

// sin(2*pi*x), cos(2*pi*x) via hardware v_sin_f32/v_cos_f32 (input in
// REVOLUTIONS, reduced to [0,1) with v_fract_f32 first).
__device__ __forceinline__ void sincos_2pi(float x, float* s, float* c) {
    float r = __builtin_amdgcn_fractf(x);
    *s = __builtin_amdgcn_sinf(r);
    *c = __builtin_amdgcn_cosf(r);
}

// Fused kernel: 4 waves share 64 points; triangles staged once per block in
// LDS (edges/2*area precomputed); waves split triangles stride-4 with
// broadcast ds_reads; wave-level rare-path split for the special cases;
// LDS 4->1 reduction; direct mag/phase output.
__global__ __launch_bounds__(BLK) void poly_cft_fused(
    const float* __restrict__ tris,    // [64,128,3,2]
    const int*   __restrict__ lengths, // [64]
    float*       __restrict__ out)     // [2*64*2048]
{
    __shared__ float4 sA[MAXN];           // xq, yq, e1x, e1y          (2 KB)
    __shared__ float4 sB[MAXN];           // e2x, e2y, 2*area, 0       (2 KB)
    __shared__ float2 s_red[NWAVE][64];   // reduction scratch         (2 KB)

    const int pg   = blockIdx.x;           // 0..31 point group
    const int b    = blockIdx.y;           // 0..63 batch elem
    const int lane = threadIdx.x & 63;
    const int wv   = threadIdx.x >> 6;     // 0..3 wave id
    const int p    = (pg << 6) | lane;     // 0..2047 freq point
    const int h    = p >> 5;
    const int w    = p & 31;

    const int N = lengths[b];

    // Stage all 128 triangles of this b (cheap: 3 KB loads, 11 VALU/lane),
    // so the hot loop never redoes det/area/edge math per (wave, triangle).
    if (threadIdx.x < MAXN) {
        const float2* tp = (const float2*)(tris + ((size_t)b * MAXN + threadIdx.x) * 6);
        const float2 v0 = tp[0], v1 = tp[1], v2 = tp[2];
        const float xq = v0.x, yq = v0.y, xr = v1.x, yr = v1.y, xs = v2.x, ys = v2.y;
        const float det  = xq * (yr - ys) + xr * (ys - yq) + xs * (yq - yr);
        const float area = fabsf(0.5f * det);
        sA[threadIdx.x] = make_float4(xq, yq, xr - xq, yr - yq);
        sB[threadIdx.x] = make_float4(xs - xr, ys - yr, 2.0f * area, 0.0f);
    }
    __syncthreads();

    // U = Wx[h], V = Wy[w] from the validated constant table.
    float U;
    if (h < 31)       U = -c_posw[30 - h];
    else if (h == 31) U = 0.0f;
    else if (h < 63)  U = c_posw[h - 32];
    else              U = 0.0f;   // padded row (masked before output)
    const float V = (w == 0) ? 0.0f : c_posw[w - 1];

    // float32 constants exactly as the reference builds them:
    const float PI_F     = 3.14159274101257324f;   // np.float32(np.pi)
    const float TWOPI    = 6.28318548202514648f;   // 2*pi_f
    const float FOUR_PI2 = (4.0f * PI_F) * PI_F;   // np.float32(4)*pi*pi

    float accR = 0.0f, accI = 0.0f;

    // Wave wv handles triangles n = wv, wv+4, ... (broadcast LDS reads).
    for (int n = wv; n < N; n += NWAVE) {
        const float4 A4 = sA[n];
        const float4 B4 = sB[n];

        // Mask-determining quantities: plain mul/mul/add (no FMA contraction)
        // to reproduce the reference's exact-zero pattern.
        const float U_ = __fadd_rn(__fmul_rn(U, A4.z), __fmul_rn(V, A4.w));
        const float V_ = __fadd_rn(__fmul_rn(U, B4.x), __fmul_rn(V, B4.y));
        const float S  = __fadd_rn(U_, V_);

        const bool uz = (U_ == 0.0f);
        const bool vz = (V_ == 0.0f);
        const bool sz = (S  == 0.0f);

        // Exponential args (not mask-relevant; FMA fine). t_r/t_s exact when
        // U_/V_ are exactly 0 (adding exact zero), as the special cases need.
        const float t_q = U * A4.x + V * A4.y;
        const float t_r = t_q + U_;
        const float t_s = t_r + V_;

        float s_q, c_q, s_r, c_r, s_s, c_s;
        sincos_2pi(t_q, &s_q, &c_q);
        sincos_2pi(t_r, &s_r, &c_r);
        sincos_2pi(t_s, &s_s, &c_s);

        if (__ballot(uz || vz || sz)) {
            // RARE path (only waves containing a U=V=0 grid point, or exact
            // float cancellations): the round-5-validated branchless 4-way
            // coefficient code, text preserved. area = 0.5f*(2*area) exact.
            const float area = 0.5f * B4.z;
            const bool zero = uz && vz;
            const bool diag = sz && !zero;
            const bool u_m  = uz && !zero;
            const bool v_m  = vz && !zero;
            const bool nrm  = !(uz || vz || sz);

            const float twU = TWOPI * U_;
            const float twV = TWOPI * V_;

            const float Ac = nrm ? -U_ : (u_m ? 1.0f : 0.0f);
            const float Bc = nrm ?  S  : ((diag || v_m) ? 1.0f : 0.0f);
            const float Cc = nrm ? -V_ : -1.0f;
            const float Dc = v_m  ? twU : 0.0f;
            const float Ec = diag ? twU : (u_m ? twV : 0.0f);

            const float d1  = u_m ? V_ : U_;
            const float den = nrm ? (U_ * V_) * S : d1 * d1;
            const float p1  = __builtin_amdgcn_rcpf(FOUR_PI2 * den);
            const float sgn = (diag || u_m) ? -2.0f : 2.0f;
            const float k   = zero ? 0.0f : sgn * area * p1;

            const float re =  Ac * c_s + Bc * c_r + Cc * c_q + Dc * s_r + Ec * s_q;
            const float im = -(Ac * s_s + Bc * s_r + Cc * s_q) + Dc * c_r + Ec * c_q;

            accR = fmaf(k, re, accR) + (zero ? area : 0.0f);
            accI = fmaf(k, im, accI);
        } else {
            // FAST path: pure normal-case algebra (Dc=Ec=0, Ac=-U_, Bc=S,
            // Cc=-V_), k = (2*area)/(4pi^2 U_ V_ S).
            const float p1 = __builtin_amdgcn_rcpf(FOUR_PI2 * ((U_ * V_) * S));
            const float k  = B4.z * p1;
            const float re = S * c_r - U_ * c_s - V_ * c_q;
            const float im = U_ * s_s - S * s_r + V_ * s_q;
            accR = fmaf(k, re, accR);
            accI = fmaf(k, im, accI);
        }
    }

    s_red[wv][lane] = make_float2(accR, accI);
    __syncthreads();

    if (wv == 0) {
        float R = 0.0f, I = 0.0f;
#pragma unroll
        for (int k = 0; k < NWAVE; ++k) {
            const float2 v = s_red[k][lane];
            R += v.x;
            I += v.y;
        }
        // numpy's masked segment-sum adds exact +0.0 for invalid slots,
        // flipping -0.0 -> +0.0; reproduce (affects only zero signs).
        R += 0.0f;
        I += 0.0f;

        if (h == 63) { R = 0.0f; I = 0.0f; }   // pad row

        const float m2 = __fadd_rn(__fmul_rn(R, R), __fmul_rn(I, I));
        float mag, ph;
        if (m2 == 0.0f) {
            mag = 0.0f;
            ph  = atan2f(I, 1.0f);   // angle(0) = 0 semantics
        } else {
            mag = log1pf(sqrtf(m2));
            ph  = atan2f(I, R);
        }

        const int o = b * NFREQ + p;
        out[o]              = mag;   // mag block [64,1,64,32]
        out[BB * NFREQ + o] = ph;    // phase block follows
    }
}

extern "C" void kernel_launch(void* const* d_in, const int* in_sizes, int n_in,
                              void* d_out, int out_size, void* d_ws, size_t ws_size,
                              hipStream_t stream) {
    const float* tris    = (const float*)d_in[0]; // [64,128,3,2] f32
    const int*   lengths = (const int*)d_in[1];   // [64] i32
    float*       out     = (float*)d_out;         // [2*64*2048] f32

    poly_cft_fused<<<dim3(PGRPS, BB), dim3(BLK), 0, stream>>>(tris, lengths, out);
}

// Round 13
// 73.990 us; speedup vs baseline: 1.0939x; 1.0218x over previous
//
#include <hip/hip_runtime.h>
#include <cmath>

// Problem constants (fixed by the reference's init kwargs):
//   POS_FREQS=31, W_MIN=0.1, W_MAX=1.0, PATCH=16 -> grid H=64 (row 63 padded), W=32
//   batch_triangles: [64,128,3,2] f32, lengths: [64] i32
//   outputs: mag [64,1,64,32] f32 then phase [64,1,64,32] f32, concatenated flat.
#define BB     64
#define MAXN   128
#define HH     64
#define WW     32
#define NFREQ  (HH*WW)      // 2048
#define BLK    256
#define NWAVE  4            // waves per block; each wave covers 64 points
#define PGRPS  (NFREQ/64)   // 32 point-groups of 64 points per batch elem

// pos_w[k] = float32(0.1 * (10^(1/30))^k) — bit-exactness validated in R10/R11.
__device__ __constant__ float c_posw[31] = {
    0.10000000000f, 0.10797751623f, 0.11659144012f, 0.12589254118f,
    0.13593563909f, 0.14677992676f, 0.15848931925f, 0.17113283042f,
    0.18478497970f, 0.19952623150f, 0.21544346900f, 0.23263050672f,
    0.25118864315f, 0.27122725793f, 0.29286445646f, 0.31622776602f,
    0.34145488738f, 0.36869450645f, 0.39810717055f, 0.42986623483f,
    0.46415888336f, 0.50118723363f, 0.54116952655f, 0.58434141336f,
    0.63095734448f, 0.68129206906f, 0.73564225446f, 0.79432823472f,
    0.85769589859f, 0.92611872813f, 1.00000000000f
};

// sin(2*pi*x), cos(2*pi*x) via hardware v_sin_f32/v_cos_f32 (input in
// REVOLUTIONS, reduced to [0,1) with v_fract_f32 first).
__device__ __forceinline__ void sincos_2pi(float x, float* s, float* c) {
    float r = __builtin_amdgcn_fractf(x);
    *s = __builtin_amdgcn_sinf(r);
    *c = __builtin_amdgcn_cosf(r);
}

// SLOW path: the round-5-validated branchless 4-way coefficient code
// (text preserved from R11's rare path; valid for ALL cases).
__device__ __forceinline__ void eval_slow(
    bool uz, bool vz, bool sz, float U_, float V_, float S, float twoArea,
    float s_q, float c_q, float s_r, float c_r, float s_s, float c_s,
    float& accR, float& accI, float TWOPI, float FOUR_PI2)
{
    const float area = 0.5f * twoArea;
    const bool zero = uz && vz;
    const bool diag = sz && !zero;
    const bool u_m  = uz && !zero;
    const bool v_m  = vz && !zero;
    const bool nrm  = !(uz || vz || sz);

    const float twU = TWOPI * U_;
    const float twV = TWOPI * V_;

    const float Ac = nrm ? -U_ : (u_m ? 1.0f : 0.0f);
    const float Bc = nrm ?  S  : ((diag || v_m) ? 1.0f : 0.0f);
    const float Cc = nrm ? -V_ : -1.0f;
    const float Dc = v_m  ? twU : 0.0f;
    const float Ec = diag ? twU : (u_m ? twV : 0.0f);

    const float d1  = u_m ? V_ : U_;
    const float den = nrm ? (U_ * V_) * S : d1 * d1;
    const float p1  = __builtin_amdgcn_rcpf(FOUR_PI2 * den);
    const float sgn = (diag || u_m) ? -2.0f : 2.0f;
    const float k   = zero ? 0.0f : sgn * area * p1;

    const float re =  Ac * c_s + Bc * c_r + Cc * c_q + Dc * s_r + Ec * s_q;
    const float im = -(Ac * s_s + Bc * s_r + Cc * s_q) + Dc * c_r + Ec * c_q;

    accR = fmaf(k, re, accR) + (zero ? area : 0.0f);
    accI = fmaf(k, im, accI);
}

// FAST path: pure normal-case algebra (validated in R11).
__device__ __forceinline__ void eval_fast(
    float U_, float V_, float S, float twoArea,
    float s_q, float c_q, float s_r, float c_r, float s_s, float c_s,
    float& accR, float& accI, float FOUR_PI2)
{
    const float p1 = __builtin_amdgcn_rcpf(FOUR_PI2 * ((U_ * V_) * S));
    const float k  = twoArea * p1;
    const float re = S * c_r - U_ * c_s - V_ * c_q;
    const float im = U_ * s_s - S * s_r + V_ * s_q;
    accR = fmaf(k, re, accR);
    accI = fmaf(k, im, accI);
}

// Fused kernel: 4 waves share 64 points; triangles staged once per block in
// LDS; waves split triangles stride-4 and process PAIRS (n, n+4) per
// iteration with a single ballot — 12 sincos + both mask computations in one
// basic block for 2-wide ILP. LDS 4->1 reduction; direct mag/phase output.
__global__ __launch_bounds__(BLK) void poly_cft_fused(
    const float* __restrict__ tris,    // [64,128,3,2]
    const int*   __restrict__ lengths, // [64]
    float*       __restrict__ out)     // [2*64*2048]
{
    __shared__ float4 sA[MAXN];           // xq, yq, e1x, e1y          (2 KB)
    __shared__ float4 sB[MAXN];           // e2x, e2y, 2*area, 0       (2 KB)
    __shared__ float2 s_red[NWAVE][64];   // reduction scratch         (2 KB)

    const int pg   = blockIdx.x;           // 0..31 point group
    const int b    = blockIdx.y;           // 0..63 batch elem
    const int lane = threadIdx.x & 63;
    const int wv   = threadIdx.x >> 6;     // 0..3 wave id
    const int p    = (pg << 6) | lane;     // 0..2047 freq point
    const int h    = p >> 5;
    const int w    = p & 31;

    const int N = lengths[b];

    // Stage all 128 triangles of this b once per block.
    if (threadIdx.x < MAXN) {
        const float2* tp = (const float2*)(tris + ((size_t)b * MAXN + threadIdx.x) * 6);
        const float2 v0 = tp[0], v1 = tp[1], v2 = tp[2];
        const float xq = v0.x, yq = v0.y, xr = v1.x, yr = v1.y, xs = v2.x, ys = v2.y;
        const float det  = xq * (yr - ys) + xr * (ys - yq) + xs * (yq - yr);
        const float area = fabsf(0.5f * det);
        sA[threadIdx.x] = make_float4(xq, yq, xr - xq, yr - yq);
        sB[threadIdx.x] = make_float4(xs - xr, ys - yr, 2.0f * area, 0.0f);
    }
    __syncthreads();

    // U = Wx[h], V = Wy[w] from the validated constant table.
    float U;
    if (h < 31)       U = -c_posw[30 - h];
    else if (h == 31) U = 0.0f;
    else if (h < 63)  U = c_posw[h - 32];
    else              U = 0.0f;   // padded row (masked before output)
    const float V = (w == 0) ? 0.0f : c_posw[w - 1];

    // float32 constants exactly as the reference builds them:
    const float PI_F     = 3.14159274101257324f;   // np.float32(np.pi)
    const float TWOPI    = 6.28318548202514648f;   // 2*pi_f
    const float FOUR_PI2 = (4.0f * PI_F) * PI_F;   // np.float32(4)*pi*pi

    float accR = 0.0f, accI = 0.0f;

    // Pair loop: wave wv evaluates (n, n+4) together; per-wave accumulation
    // order (wv, wv+4, wv+8, ...) is preserved exactly.
    int n = wv;
    for (; n < N - NWAVE; n += 2 * NWAVE) {
        const float4 Aa = sA[n],         Ba = sB[n];
        const float4 Ab = sA[n + NWAVE], Bb = sB[n + NWAVE];

        // Mask-determining quantities: plain mul/mul/add (no FMA contraction).
        const float Ua = __fadd_rn(__fmul_rn(U, Aa.z), __fmul_rn(V, Aa.w));
        const float Va = __fadd_rn(__fmul_rn(U, Ba.x), __fmul_rn(V, Ba.y));
        const float Sa = __fadd_rn(Ua, Va);
        const float Ub = __fadd_rn(__fmul_rn(U, Ab.z), __fmul_rn(V, Ab.w));
        const float Vb = __fadd_rn(__fmul_rn(U, Bb.x), __fmul_rn(V, Bb.y));
        const float Sb = __fadd_rn(Ub, Vb);

        const bool uza = (Ua == 0.0f), vza = (Va == 0.0f), sza = (Sa == 0.0f);
        const bool uzb = (Ub == 0.0f), vzb = (Vb == 0.0f), szb = (Sb == 0.0f);

        const float tqa = U * Aa.x + V * Aa.y;
        const float tra = tqa + Ua;
        const float tsa = tra + Va;
        const float tqb = U * Ab.x + V * Ab.y;
        const float trb = tqb + Ub;
        const float tsb = trb + Vb;

        float sqa, cqa, sra, cra, ssa, csa;
        float sqb, cqb, srb, crb, ssb, csb;
        sincos_2pi(tqa, &sqa, &cqa);
        sincos_2pi(tra, &sra, &cra);
        sincos_2pi(tsa, &ssa, &csa);
        sincos_2pi(tqb, &sqb, &cqb);
        sincos_2pi(trb, &srb, &crb);
        sincos_2pi(tsb, &ssb, &csb);

        if (__ballot(uza || vza || sza || uzb || vzb || szb)) {
            eval_slow(uza, vza, sza, Ua, Va, Sa, Ba.z,
                      sqa, cqa, sra, cra, ssa, csa, accR, accI, TWOPI, FOUR_PI2);
            eval_slow(uzb, vzb, szb, Ub, Vb, Sb, Bb.z,
                      sqb, cqb, srb, crb, ssb, csb, accR, accI, TWOPI, FOUR_PI2);
        } else {
            eval_fast(Ua, Va, Sa, Ba.z, sqa, cqa, sra, cra, ssa, csa,
                      accR, accI, FOUR_PI2);
            eval_fast(Ub, Vb, Sb, Bb.z, sqb, cqb, srb, crb, ssb, csb,
                      accR, accI, FOUR_PI2);
        }
    }

    // Remainder (at most one triangle per wave).
    for (; n < N; n += NWAVE) {
        const float4 A4 = sA[n], B4 = sB[n];
        const float U_ = __fadd_rn(__fmul_rn(U, A4.z), __fmul_rn(V, A4.w));
        const float V_ = __fadd_rn(__fmul_rn(U, B4.x), __fmul_rn(V, B4.y));
        const float S  = __fadd_rn(U_, V_);
        const bool uz = (U_ == 0.0f), vz = (V_ == 0.0f), sz = (S == 0.0f);

        const float t_q = U * A4.x + V * A4.y;
        const float t_r = t_q + U_;
        const float t_s = t_r + V_;
        float s_q, c_q, s_r, c_r, s_s, c_s;
        sincos_2pi(t_q, &s_q, &c_q);
        sincos_2pi(t_r, &s_r, &c_r);
        sincos_2pi(t_s, &s_s, &c_s);

        if (__ballot(uz || vz || sz)) {
            eval_slow(uz, vz, sz, U_, V_, S, B4.z,
                      s_q, c_q, s_r, c_r, s_s, c_s, accR, accI, TWOPI, FOUR_PI2);
        } else {
            eval_fast(U_, V_, S, B4.z, s_q, c_q, s_r, c_r, s_s, c_s,
                      accR, accI, FOUR_PI2);
        }
    }

    s_red[wv][lane] = make_float2(accR, accI);
    __syncthreads();

    if (wv == 0) {
        float R = 0.0f, I = 0.0f;
#pragma unroll
        for (int k = 0; k < NWAVE; ++k) {
            const float2 v = s_red[k][lane];
            R += v.x;
            I += v.y;
        }
        // numpy's masked segment-sum adds exact +0.0 for invalid slots,
        // flipping -0.0 -> +0.0; reproduce (affects only zero signs).
        R += 0.0f;
        I += 0.0f;

        if (h == 63) { R = 0.0f; I = 0.0f; }   // pad row

        const float m2 = __fadd_rn(__fmul_rn(R, R), __fmul_rn(I, I));
        float mag, ph;
        if (m2 == 0.0f) {
            mag = 0.0f;
            ph  = atan2f(I, 1.0f);   // angle(0) = 0 semantics
        } else {
            mag = log1pf(sqrtf(m2));
            ph  = atan2f(I, R);
        }

        const int o = b * NFREQ + p;
        out[o]              = mag;   // mag block [64,1,64,32]
        out[BB * NFREQ + o] = ph;    // phase block follows
    }
}

extern "C" void kernel_launch(void* const* d_in, const int* in_sizes, int n_in,
                              void* d_out, int out_size, void* d_ws, size_t ws_size,
                              hipStream_t stream) {
    const float* tris    = (const float*)d_in[0]; // [64,128,3,2] f32
    const int*   lengths = (const int*)d_in[1];   // [64] i32
    float*       out     = (float*)d_out;         // [2*64*2048] f32

    poly_cft_fused<<<dim3(PGRPS, BB), dim3(BLK), 0, stream>>>(tris, lengths, out);
}

// Round 14
// 73.861 us; speedup vs baseline: 1.0958x; 1.0017x over previous
//
#include <hip/hip_runtime.h>
#include <cmath>

// Problem constants (fixed by the reference's init kwargs):
//   POS_FREQS=31, W_MIN=0.1, W_MAX=1.0, PATCH=16 -> grid H=64 (row 63 padded), W=32
//   batch_triangles: [64,128,3,2] f32, lengths: [64] i32
//   outputs: mag [64,1,64,32] f32 then phase [64,1,64,32] f32, concatenated flat.
#define BB     64
#define MAXN   128
#define HH     64
#define WW     32
#define NFREQ  (HH*WW)      // 2048
#define BLK    256
#define NWAVE  4            // waves per block; each wave covers 64 points
#define PGRPS  (NFREQ/64)   // 32 point-groups of 64 points per batch elem

// pos_w[k] = float32(0.1 * (10^(1/30))^k) — bit-exactness validated in R10/R11.
__device__ __constant__ float c_posw[31] = {
    0.10000000000f, 0.10797751623f, 0.11659144012f, 0.12589254118f,
    0.13593563909f, 0.14677992676f, 0.15848931925f, 0.17113283042f,
    0.18478497970f, 0.19952623150f, 0.21544346900f, 0.23263050672f,
    0.25118864315f, 0.27122725793f, 0.29286445646f, 0.31622776602f,
    0.34145488738f, 0.36869450645f, 0.39810717055f, 0.42986623483f,
    0.46415888336f, 0.50118723363f, 0.54116952655f, 0.58434141336f,
    0.63095734448f, 0.68129206906f, 0.73564225446f, 0.79432823472f,
    0.85769589859f, 0.92611872813f, 1.00000000000f
};

// float32 constants exactly as the reference builds them:
#define PI_F      3.14159274101257324f   // np.float32(np.pi)
#define TWOPI_F   6.28318548202514648f   // 2*pi_f
#define FOURPI2_F ((4.0f * PI_F) * PI_F) // np.float32(4)*pi*pi

// sin(2*pi*x), cos(2*pi*x) via hardware v_sin_f32/v_cos_f32 (input in
// REVOLUTIONS, reduced to [0,1) with v_fract_f32 first).
__device__ __forceinline__ void sincos_2pi(float x, float* s, float* c) {
    float r = __builtin_amdgcn_fractf(x);
    *s = __builtin_amdgcn_sinf(r);
    *c = __builtin_amdgcn_cosf(r);
}

// Per-triangle precomputation shared by both paths: mask quantities
// (exact mul/mul/add, no FMA contraction), 3 sincos, staged constants.
struct Pre {
    float U_, V_, S;
    float z2;              // 2*area (exact)
    float zk;              // 2*area/(4pi^2) (pre-scaled for the fast path)
    float sq, cq, sr, cr, ss, cs;
    bool  uz, vz, sz, sp;
};

__device__ __forceinline__ Pre pre_eval(float U, float V, float4 A4, float4 B4) {
    Pre e;
    e.U_ = __fadd_rn(__fmul_rn(U, A4.z), __fmul_rn(V, A4.w));
    e.V_ = __fadd_rn(__fmul_rn(U, B4.x), __fmul_rn(V, B4.y));
    e.S  = __fadd_rn(e.U_, e.V_);
    e.uz = (e.U_ == 0.0f);
    e.vz = (e.V_ == 0.0f);
    e.sz = (e.S  == 0.0f);
    e.sp = e.uz || e.vz || e.sz;
    // Exponential args (not mask-relevant; FMA fine). t_r/t_s exact when
    // U_/V_ are exactly 0 (adding exact zero), as the special cases need.
    const float tq = U * A4.x + V * A4.y;
    const float tr = tq + e.U_;
    const float ts = tr + e.V_;
    sincos_2pi(tq, &e.sq, &e.cq);
    sincos_2pi(tr, &e.sr, &e.cr);
    sincos_2pi(ts, &e.ss, &e.cs);
    e.z2 = B4.z;
    e.zk = B4.w;
    return e;
}

// SLOW path: the round-5-validated branchless 4-way coefficient code
// (text preserved; valid for ALL cases). area = 0.5f*(2*area) exact.
__device__ __forceinline__ void eval_slow(const Pre& e, float& accR, float& accI) {
    const float area = 0.5f * e.z2;
    const bool zero = e.uz && e.vz;
    const bool diag = e.sz && !zero;
    const bool u_m  = e.uz && !zero;
    const bool v_m  = e.vz && !zero;
    const bool nrm  = !(e.uz || e.vz || e.sz);

    const float twU = TWOPI_F * e.U_;
    const float twV = TWOPI_F * e.V_;

    const float Ac = nrm ? -e.U_ : (u_m ? 1.0f : 0.0f);
    const float Bc = nrm ?  e.S  : ((diag || v_m) ? 1.0f : 0.0f);
    const float Cc = nrm ? -e.V_ : -1.0f;
    const float Dc = v_m  ? twU : 0.0f;
    const float Ec = diag ? twU : (u_m ? twV : 0.0f);

    const float d1  = u_m ? e.V_ : e.U_;
    const float den = nrm ? (e.U_ * e.V_) * e.S : d1 * d1;
    const float p1  = __builtin_amdgcn_rcpf(FOURPI2_F * den);
    const float sgn = (diag || u_m) ? -2.0f : 2.0f;
    const float k   = zero ? 0.0f : sgn * area * p1;

    const float re =  Ac * e.cs + Bc * e.cr + Cc * e.cq + Dc * e.sr + Ec * e.sq;
    const float im = -(Ac * e.ss + Bc * e.sr + Cc * e.sq) + Dc * e.cr + Ec * e.cq;

    accR = fmaf(k, re, accR) + (zero ? area : 0.0f);
    accI = fmaf(k, im, accI);
}

// FAST path: pure normal-case algebra; k = (2*area/4pi^2) * rcp(U_ V_ S).
__device__ __forceinline__ void eval_fast(const Pre& e, float& accR, float& accI) {
    const float p1 = __builtin_amdgcn_rcpf((e.U_ * e.V_) * e.S);
    const float k  = e.zk * p1;
    const float re = e.S * e.cr - e.U_ * e.cs - e.V_ * e.cq;
    const float im = e.U_ * e.ss - e.S * e.sr + e.V_ * e.sq;
    accR = fmaf(k, re, accR);
    accI = fmaf(k, im, accI);
}

// Fused kernel: 4 waves share 64 points; triangles staged once per block in
// LDS; waves split triangles stride-4 and process QUADS (n,n+4,n+8,n+12)
// per iteration with a single ballot — 12 sincos + 4 mask computations in
// one basic block for 4-wide ILP. LDS 4->1 reduction; direct output.
__global__ __launch_bounds__(BLK) void poly_cft_fused(
    const float* __restrict__ tris,    // [64,128,3,2]
    const int*   __restrict__ lengths, // [64]
    float*       __restrict__ out)     // [2*64*2048]
{
    __shared__ float4 sA[MAXN];           // xq, yq, e1x, e1y          (2 KB)
    __shared__ float4 sB[MAXN];           // e2x, e2y, 2a, 2a/4pi^2    (2 KB)
    __shared__ float2 s_red[NWAVE][64];   // reduction scratch         (2 KB)

    const int pg   = blockIdx.x;           // 0..31 point group
    const int b    = blockIdx.y;           // 0..63 batch elem
    const int lane = threadIdx.x & 63;
    const int wv   = threadIdx.x >> 6;     // 0..3 wave id
    const int p    = (pg << 6) | lane;     // 0..2047 freq point
    const int h    = p >> 5;
    const int w    = p & 31;

    const int N = lengths[b];

    // Stage all 128 triangles of this b once per block.
    if (threadIdx.x < MAXN) {
        const float2* tp = (const float2*)(tris + ((size_t)b * MAXN + threadIdx.x) * 6);
        const float2 v0 = tp[0], v1 = tp[1], v2 = tp[2];
        const float xq = v0.x, yq = v0.y, xr = v1.x, yr = v1.y, xs = v2.x, ys = v2.y;
        const float det  = xq * (yr - ys) + xr * (ys - yq) + xs * (yq - yr);
        const float area = fabsf(0.5f * det);
        const float a2   = 2.0f * area;
        sA[threadIdx.x] = make_float4(xq, yq, xr - xq, yr - yq);
        sB[threadIdx.x] = make_float4(xs - xr, ys - yr, a2, a2 * (1.0f / FOURPI2_F));
    }
    __syncthreads();

    // U = Wx[h], V = Wy[w] from the validated constant table.
    float U;
    if (h < 31)       U = -c_posw[30 - h];
    else if (h == 31) U = 0.0f;
    else if (h < 63)  U = c_posw[h - 32];
    else              U = 0.0f;   // padded row (masked before output)
    const float V = (w == 0) ? 0.0f : c_posw[w - 1];

    float accR = 0.0f, accI = 0.0f;

    // Quad loop: wave wv evaluates (n, n+4, n+8, n+12) together; per-wave
    // accumulation order (wv, wv+4, wv+8, ...) is preserved exactly.
    int n = wv;
    for (; n + 3 * NWAVE < N; n += 4 * NWAVE) {
        const Pre ea = pre_eval(U, V, sA[n],             sB[n]);
        const Pre eb = pre_eval(U, V, sA[n +     NWAVE], sB[n +     NWAVE]);
        const Pre ec = pre_eval(U, V, sA[n + 2 * NWAVE], sB[n + 2 * NWAVE]);
        const Pre ed = pre_eval(U, V, sA[n + 3 * NWAVE], sB[n + 3 * NWAVE]);

        if (__ballot(ea.sp || eb.sp || ec.sp || ed.sp)) {
            eval_slow(ea, accR, accI);
            eval_slow(eb, accR, accI);
            eval_slow(ec, accR, accI);
            eval_slow(ed, accR, accI);
        } else {
            eval_fast(ea, accR, accI);
            eval_fast(eb, accR, accI);
            eval_fast(ec, accR, accI);
            eval_fast(ed, accR, accI);
        }
    }

    // Pair remainder.
    for (; n + NWAVE < N; n += 2 * NWAVE) {
        const Pre ea = pre_eval(U, V, sA[n],         sB[n]);
        const Pre eb = pre_eval(U, V, sA[n + NWAVE], sB[n + NWAVE]);
        if (__ballot(ea.sp || eb.sp)) {
            eval_slow(ea, accR, accI);
            eval_slow(eb, accR, accI);
        } else {
            eval_fast(ea, accR, accI);
            eval_fast(eb, accR, accI);
        }
    }

    // Single remainder (at most one triangle per wave).
    for (; n < N; n += NWAVE) {
        const Pre ea = pre_eval(U, V, sA[n], sB[n]);
        if (__ballot(ea.sp)) {
            eval_slow(ea, accR, accI);
        } else {
            eval_fast(ea, accR, accI);
        }
    }

    s_red[wv][lane] = make_float2(accR, accI);
    __syncthreads();

    if (wv == 0) {
        float R = 0.0f, I = 0.0f;
#pragma unroll
        for (int k = 0; k < NWAVE; ++k) {
            const float2 v = s_red[k][lane];
            R += v.x;
            I += v.y;
        }
        // numpy's masked segment-sum adds exact +0.0 for invalid slots,
        // flipping -0.0 -> +0.0; reproduce (affects only zero signs).
        R += 0.0f;
        I += 0.0f;

        if (h == 63) { R = 0.0f; I = 0.0f; }   // pad row

        const float m2 = __fadd_rn(__fmul_rn(R, R), __fmul_rn(I, I));
        float mag, ph;
        if (m2 == 0.0f) {
            mag = 0.0f;
            ph  = atan2f(I, 1.0f);   // angle(0) = 0 semantics
        } else {
            mag = log1pf(sqrtf(m2));
            ph  = atan2f(I, R);
        }

        const int o = b * NFREQ + p;
        out[o]              = mag;   // mag block [64,1,64,32]
        out[BB * NFREQ + o] = ph;    // phase block follows
    }
}

extern "C" void kernel_launch(void* const* d_in, const int* in_sizes, int n_in,
                              void* d_out, int out_size, void* d_ws, size_t ws_size,
                              hipStream_t stream) {
    const float* tris    = (const float*)d_in[0]; // [64,128,3,2] f32
    const int*   lengths = (const int*)d_in[1];   // [64] i32
    float*       out     = (float*)d_out;         // [2*64*2048] f32

    poly_cft_fused<<<dim3(PGRPS, BB), dim3(BLK), 0, stream>>>(tris, lengths, out);
}